// Round 9
// baseline (65.266 us; speedup 1.0000x reference)
//
#include <hip/hip_runtime.h>
#include <stdint.h>

#define C_    19
#define NB    15
#define CB    (C_ * NB)          // 285 cells
#define HW    (512 * 1024)
#define NPIX  (4 * HW)           // 2097152
#define TPB   256
#define TILE  256                // pixels per tile (1 px/thread/tile)
#define ROWS  20                 // 19 logit rows + 1 label row
#define NT    8                  // tiles per block
#define GBLK  (NPIX / (TILE * NT))   // 1024 blocks
#define REPS  4                  // LDS replicas for rare bin>=4 atomics
#define KCOP  8                  // global histogram copies

// DMA-staged ECE, v2 fixed: bins 0-3 in registers (LDS atomics only for
// bin>=4, ~0.33/pixel), CORRECT tree exp-sum. global_load_lds 16 B/lane,
// double-buffered, counted vmcnt + raw s_barrier (no __syncthreads drain).
// Merged-cell: cell += conf - (c==label); final = sum |cell| / (N*C).
__global__ __launch_bounds__(TPB, 3)
void ece_hist(const float* __restrict__ logits,
              const int*   __restrict__ labels,
              float*       __restrict__ ws) {
    __shared__ uint32_t tile[2][ROWS][TILE];   // 40960 B
    __shared__ float    hist[REPS * CB];       //  4560 B

    const int tid  = threadIdx.x;
    const int wave = tid >> 6;
    const int lane = tid & 63;

    for (int i = tid; i < REPS * CB; i += TPB) hist[i] = 0.f;
    __syncthreads();                            // before any staging; safe here

    float* myh = hist + (tid & (REPS - 1)) * CB;

    float d0[C_], d1[C_], d2[C_], d3[C_];       // merged accumulators, bins 0-3
#pragma unroll
    for (int c = 0; c < C_; ++c) { d0[c] = 0.f; d1[c] = 0.f; d2[c] = 0.f; d3[c] = 0.f; }

    // Stage tile t into buffer bb: wave w loads rows 5w..5w+4 (row 19 = labels).
    auto STAGE = [&](int t, int bb) {
        const int n0 = (blockIdx.x * NT + t) * TILE;
        const int b  = n0 >> 19;                // HW = 2^19; tiles never straddle b
        const int hw = n0 & (HW - 1);
#pragma unroll
        for (int k = 0; k < 5; ++k) {
            const int r = wave * 5 + k;
            const uint32_t* src = (r < C_)
                ? (const uint32_t*)(logits + ((size_t)b * C_ + r) * HW + hw) + lane * 4
                : (const uint32_t*)(labels + n0) + lane * 4;
            __builtin_amdgcn_global_load_lds(
                (const __attribute__((address_space(1))) void*)src,
                (__attribute__((address_space(3))) void*)&tile[bb][r][0],
                16, 0, 0);                      // lane i lands at base + i*16
        }
    };

    STAGE(0, 0);
    for (int t = 0; t < NT; ++t) {
        const int cur = t & 1;
        if (t + 1 < NT) {
            STAGE(t + 1, cur ^ 1);
            asm volatile("s_waitcnt vmcnt(5)" ::: "memory");  // tile t landed; t+1 in flight
        } else {
            asm volatile("s_waitcnt vmcnt(0)" ::: "memory");
        }
        __builtin_amdgcn_s_barrier();           // all waves' rows present
        __builtin_amdgcn_sched_barrier(0);      // no hoisting of reads above barrier

        float x[C_];
#pragma unroll
        for (int c = 0; c < C_; ++c) x[c] = __uint_as_float(tile[cur][c][tid]);
        const int l = (int)tile[cur][C_][tid];

#pragma unroll
        for (int c = 0; c < C_; ++c) x[c] = __expf(x[c]);

        // pairwise-tree sum: a[0]=x0..7, a[4]=x8..15, a[8]=x16..18 (all 19 terms)
        float a[10];
#pragma unroll
        for (int j = 0; j < 9; ++j) a[j] = x[2 * j] + x[2 * j + 1];
        a[9] = x[18];
        a[0] += a[1]; a[2] += a[3]; a[4] += a[5]; a[6] += a[7]; a[8] += a[9];
        a[0] += a[2]; a[4] += a[6];
        const float inv = 1.f / (a[0] + a[4] + a[8]);

#pragma unroll
        for (int c = 0; c < C_; ++c) {
            const float conf = x[c] * inv;
            int bin = (int)ceilf(conf * (float)NB) - 1;      // reference binning
            bin = bin < 0 ? 0 : (bin > NB - 1 ? NB - 1 : bin);
            const float val = conf - ((c == l) ? 1.f : 0.f);
            d0[c] += (bin == 0) ? val : 0.f;
            d1[c] += (bin == 1) ? val : 0.f;
            d2[c] += (bin == 2) ? val : 0.f;
            d3[c] += (bin == 3) ? val : 0.f;
            if (bin >= 4) atomicAdd(&myh[c * NB + bin], val);  // ~0.33/pixel total
        }

        __builtin_amdgcn_s_barrier();           // done reading buf before overwrite
    }

    // Flush: 3-step xor-shuffle (8-lane groups) -> leader ds-atomics into replicas.
#pragma unroll
    for (int c = 0; c < C_; ++c) {
        float v0 = d0[c], v1 = d1[c], v2 = d2[c], v3 = d3[c];
        v0 += __shfl_xor(v0, 1); v1 += __shfl_xor(v1, 1); v2 += __shfl_xor(v2, 1); v3 += __shfl_xor(v3, 1);
        v0 += __shfl_xor(v0, 2); v1 += __shfl_xor(v1, 2); v2 += __shfl_xor(v2, 2); v3 += __shfl_xor(v3, 2);
        v0 += __shfl_xor(v0, 4); v1 += __shfl_xor(v1, 4); v2 += __shfl_xor(v2, 4); v3 += __shfl_xor(v3, 4);
        if ((tid & 7) == 0) {
            const int r = (tid >> 3) & (REPS - 1);
            atomicAdd(&hist[r * CB + c * NB + 0], v0);
            atomicAdd(&hist[r * CB + c * NB + 1], v1);
            atomicAdd(&hist[r * CB + c * NB + 2], v2);
            atomicAdd(&hist[r * CB + c * NB + 3], v3);
        }
    }
    __syncthreads();

    // Fold replicas -> one global atomic per cell into one of KCOP copies.
    float* wsb = ws + (size_t)(blockIdx.x & (KCOP - 1)) * CB;
    for (int i = tid; i < CB; i += TPB) {
        float s = 0.f;
#pragma unroll
        for (int r = 0; r < REPS; ++r) s += hist[r * CB + i];
        atomicAdd(&wsb[i], s);
    }
}

// Fold KCOP copies: sce = sum_cells |cell| / (N * C)
__global__ void ece_final(const float* __restrict__ ws, float* __restrict__ out) {
    const int t = threadIdx.x;  // 320 threads = 5 waves
    float val = 0.f;
    if (t < CB) {
        float s = 0.f;
#pragma unroll
        for (int k = 0; k < KCOP; ++k) s += ws[k * CB + t];
        val = fabsf(s);
    }
#pragma unroll
    for (int off = 32; off; off >>= 1) val += __shfl_down(val, off);
    __shared__ float sm[5];
    if ((t & 63) == 0) sm[t >> 6] = val;
    __syncthreads();
    if (t == 0) {
        float tot = sm[0] + sm[1] + sm[2] + sm[3] + sm[4];
        out[0] = tot / ((float)NPIX * (float)C_);
    }
}

extern "C" void kernel_launch(void* const* d_in, const int* in_sizes, int n_in,
                              void* d_out, int out_size, void* d_ws, size_t ws_size,
                              hipStream_t stream) {
    const float* logits = (const float*)d_in[0];
    const int*   labels = (const int*)d_in[1];
    float* out = (float*)d_out;
    float* ws  = (float*)d_ws;

    hipMemsetAsync(ws, 0, (size_t)KCOP * CB * sizeof(float), stream);
    ece_hist<<<GBLK, TPB, 0, stream>>>(logits, labels, ws);
    ece_final<<<1, 320, 0, stream>>>(ws, out);
}

// Round 10
// 57.607 us; speedup vs baseline: 1.1330x; 1.1330x over previous
//
#include <hip/hip_runtime.h>
#include <stdint.h>

#define C_    19
#define NB    15
#define CB    (C_ * NB)          // 285 cells
#define HW    (512 * 1024)
#define NPIX  (4 * HW)           // 2097152
#define TPB   256                // 4 waves
#define WTILE 64                 // pixels per wave-tile (1 px/lane)
#define ROWS  20                 // 19 logit rows + 1 label row
#define NT    8                  // tiles per wave
#define GBLK  (NPIX / (WTILE * NT * 4))   // 1024 blocks
#define REPS  4                  // LDS replicas for bin>=2 atomics
#define KCOP  8                  // global histogram copies

// Wave-private DMA pipeline: each wave double-buffers its own 64-px tile via
// width-4 global_load_lds and gates ONLY itself with counted vmcnt -- zero
// barriers in the main loop. 12 independent wave-pipelines/CU replace the
// R7 lock-stepped block pipeline (suspected 2x gap).
// Merged-cell: cell += conf - (c==label); bins 0/1 in regs, bin>=2 via LDS.
__global__ __launch_bounds__(TPB, 3)
void ece_hist(const float* __restrict__ logits,
              const int*   __restrict__ labels,
              float*       __restrict__ ws) {
    __shared__ uint32_t tile[4][2][ROWS][WTILE];  // 40960 B (per-wave dbuf)
    __shared__ float    hist[REPS * CB];          //  4560 B

    const int tid  = threadIdx.x;
    const int wave = tid >> 6;
    const int lane = tid & 63;

    for (int i = tid; i < REPS * CB; i += TPB) hist[i] = 0.f;
    __syncthreads();                              // hist zeroed before any atomics

    float* myh = hist + (tid & (REPS - 1)) * CB;

    float d0[C_], d1[C_];                         // merged accumulators, bins 0/1
#pragma unroll
    for (int c = 0; c < C_; ++c) { d0[c] = 0.f; d1[c] = 0.f; }

    // Stage this wave's tile t into its buffer bb: 20 width-4 DMA rows.
    auto STAGE = [&](int t, int bb) {
        const int n0 = ((blockIdx.x * 4 + wave) * NT + t) * WTILE;
        const int b  = n0 >> 19;                  // HW = 2^19; 64-px tiles never straddle
        const int hw = n0 & (HW - 1);
#pragma unroll
        for (int r = 0; r < ROWS; ++r) {
            const uint32_t* src = (r < C_)
                ? (const uint32_t*)(logits + ((size_t)b * C_ + r) * HW + hw) + lane
                : (const uint32_t*)(labels + n0) + lane;
            __builtin_amdgcn_global_load_lds(
                (const __attribute__((address_space(1))) void*)src,
                (__attribute__((address_space(3))) void*)&tile[wave][bb][r][0],
                4, 0, 0);                         // lane i -> base + 4i
        }
    };

    STAGE(0, 0);
    for (int t = 0; t < NT; ++t) {
        const int cur = t & 1;
        if (t + 1 < NT) {
            STAGE(t + 1, cur ^ 1);
            asm volatile("s_waitcnt vmcnt(20)" ::: "memory");  // tile t landed; t+1 in flight
        } else {
            asm volatile("s_waitcnt vmcnt(0)" ::: "memory");
        }
        __builtin_amdgcn_sched_barrier(0);        // keep ds_reads below the wait

        float x[C_];
#pragma unroll
        for (int c = 0; c < C_; ++c) x[c] = __uint_as_float(tile[wave][cur][c][lane]);
        const int l = (int)tile[wave][cur][C_][lane];

#pragma unroll
        for (int c = 0; c < C_; ++c) x[c] = __expf(x[c]);

        // pairwise-tree sum: a[0]=x0..7, a[4]=x8..15, a[8]=x16..18
        float a[10];
#pragma unroll
        for (int j = 0; j < 9; ++j) a[j] = x[2 * j] + x[2 * j + 1];
        a[9] = x[18];
        a[0] += a[1]; a[2] += a[3]; a[4] += a[5]; a[6] += a[7]; a[8] += a[9];
        a[0] += a[2]; a[4] += a[6];
        const float inv = 1.f / (a[0] + a[4] + a[8]);

#pragma unroll
        for (int c = 0; c < C_; ++c) {
            const float conf = x[c] * inv;
            int bin = (int)ceilf(conf * (float)NB) - 1;      // reference binning
            bin = bin < 0 ? 0 : (bin > NB - 1 ? NB - 1 : bin);
            const float val = conf - ((c == l) ? 1.f : 0.f);
            d0[c] += (bin == 0) ? val : 0.f;
            d1[c] += (bin == 1) ? val : 0.f;
            if (bin >= 2) atomicAdd(&myh[c * NB + bin], val);  // ~1.5/pixel
        }
        // no barrier: buffers are wave-private
    }

    // Flush: 3-step xor-shuffle (8-lane groups) -> leader ds-atomics into replicas.
#pragma unroll
    for (int c = 0; c < C_; ++c) {
        float v0 = d0[c], v1 = d1[c];
        v0 += __shfl_xor(v0, 1); v1 += __shfl_xor(v1, 1);
        v0 += __shfl_xor(v0, 2); v1 += __shfl_xor(v1, 2);
        v0 += __shfl_xor(v0, 4); v1 += __shfl_xor(v1, 4);
        if ((tid & 7) == 0) {
            const int r = (tid >> 3) & (REPS - 1);
            atomicAdd(&hist[r * CB + c * NB + 0], v0);
            atomicAdd(&hist[r * CB + c * NB + 1], v1);
        }
    }
    __syncthreads();

    // Fold replicas -> one global atomic per cell into one of KCOP copies.
    float* wsb = ws + (size_t)(blockIdx.x & (KCOP - 1)) * CB;
    for (int i = tid; i < CB; i += TPB) {
        float s = 0.f;
#pragma unroll
        for (int r = 0; r < REPS; ++r) s += hist[r * CB + i];
        atomicAdd(&wsb[i], s);
    }
}

// Fold KCOP copies: sce = sum_cells |cell| / (N * C)
__global__ void ece_final(const float* __restrict__ ws, float* __restrict__ out) {
    const int t = threadIdx.x;  // 320 threads = 5 waves
    float val = 0.f;
    if (t < CB) {
        float s = 0.f;
#pragma unroll
        for (int k = 0; k < KCOP; ++k) s += ws[k * CB + t];
        val = fabsf(s);
    }
#pragma unroll
    for (int off = 32; off; off >>= 1) val += __shfl_down(val, off);
    __shared__ float sm[5];
    if ((t & 63) == 0) sm[t >> 6] = val;
    __syncthreads();
    if (t == 0) {
        float tot = sm[0] + sm[1] + sm[2] + sm[3] + sm[4];
        out[0] = tot / ((float)NPIX * (float)C_);
    }
}

extern "C" void kernel_launch(void* const* d_in, const int* in_sizes, int n_in,
                              void* d_out, int out_size, void* d_ws, size_t ws_size,
                              hipStream_t stream) {
    const float* logits = (const float*)d_in[0];
    const int*   labels = (const int*)d_in[1];
    float* out = (float*)d_out;
    float* ws  = (float*)d_ws;

    hipMemsetAsync(ws, 0, (size_t)KCOP * CB * sizeof(float), stream);
    ece_hist<<<GBLK, TPB, 0, stream>>>(logits, labels, ws);
    ece_final<<<1, 320, 0, stream>>>(ws, out);
}